// Round 8
// baseline (397.071 us; speedup 1.0000x reference)
//
#include <hip/hip_runtime.h>
#include <math.h>

#define NF 32
#define NN 4096
#define ND 64
#define NK 512

// loss = q_latent + 0.25 * e_latent = 1.25 * mean((q - x)^2)
#define LOSS_SCALE (1.25f / (float)(NF * NN * ND))
// rescue margin, tested in the PACKED-KEY domain: exact-score margin
// TAU=3e-4 (3-term split-bf16 err) + 2x col-pack trunc quantum
// (|s| <= ~3 -> q <= 1.3e-4): flag if s2' - s1' < 5.5e-4. Strictly
// conservative vs the exact-gap test (collisions/ties always flagged).
#define RESCUE_TAU 5.5e-4f

typedef short bf16x8 __attribute__((ext_vector_type(8)));
typedef float f32x4 __attribute__((ext_vector_type(4)));

static __device__ __forceinline__ unsigned short f2bf_rne(float f) {
    unsigned int u = __float_as_uint(f);
    u += 0x7FFFu + ((u >> 16) & 1u);
    return (unsigned short)(u >> 16);
}
static __device__ __forceinline__ float bf2f(unsigned short h) {
    return __uint_as_float(((unsigned int)h) << 16);
}

// async global->LDS: 16B per lane, dest = wave-uniform base + lane*16
static __device__ __forceinline__ void gload_lds16(const void* g, void* l) {
    __builtin_amdgcn_global_load_lds(
        (const __attribute__((address_space(1))) unsigned int*)g,
        (__attribute__((address_space(3))) unsigned int*)l, 16, 0, 0);
}

// ---------------------------------------------------------------------------
// SINGLE FUSED KERNEL (v8). R7 showed ~16us/dispatch overhead; the 2-kernel
// pipeline still paid prep_w + one dispatch. Key insight: argmin block
// (f, xt) needs only f's codebook, and #argmin blocks per f (32) ==
// #prep units per f (32). So each block preps unit (f, kq=xt) (16 cols x
// 64 d transpose + bf16 split + 0.5||w||^2), then syncs with its f-group
// via a per-f device-scope counter. Co-residency is guaranteed by
// construction: grid 1024 = 4 blocks/CU x 256 CU, __launch_bounds__(256,4),
// LDS 19.5KB (8/CU possible), VGPR well under the 4-waves/SIMD cap -> all
// blocks resident, spin cannot deadlock. Counters zeroed by a capture-safe
// hipMemsetAsync before launch.
// Phases (per block): prep -> f-sync -> 16-supertile dbuf MFMA loop (R7,
// with SLIM 2-channel packed-key top-2: pack+med3+min = 3 VALU/score vs 4)
// -> merge -> in-LDS keys/flags -> wave-local exact rescue -> gather +
// loss (ws accumulator; last-done block writes the scalar).
// ---------------------------------------------------------------------------
__global__ __launch_bounds__(256, 4)
void vq_fused(const float* __restrict__ x_in, const float* __restrict__ w,
              float* __restrict__ wt, unsigned short* __restrict__ wh,
              unsigned short* __restrict__ wl, float* __restrict__ w2h,
              unsigned int* __restrict__ syncws,
              float* __restrict__ out, float* __restrict__ loss_slot) {
    const int b    = blockIdx.x;          // [0, 1024)
    const int j    = b >> 3;              // [0, 128)
    const int f    = (b & 7) * 4 + (j & 3);
    const int xt   = j >> 2;              // [0, 32)
    const int tid  = threadIdx.x;
    const int wave = tid >> 6;
    const int lane = tid & 63;
    const int lc   = lane & 15;
    const int q    = lane >> 4;
    const int n0   = xt * 128 + wave * 32;   // wave's private 32 rows
    const int g0b  = f * NN + xt * 128;      // block's global row base

    __shared__ float w2s[NK];                                 // 2 KB
    __shared__ __align__(16) unsigned short bstage[2][4096];  // 2 x 8 KB
    __shared__ unsigned int lds_key[128];                     // 512 B
    __shared__ unsigned char lds_flag[128];                   // 128 B
    __shared__ float wsum[4];

    // ---- A-frags first: x loads in flight during prep compute + sync.
    bf16x8 ah[2][2], al[2][2];
    const float* __restrict__ xbase = x_in + ((size_t)f * NN + n0 + lc) * ND;
#pragma unroll
    for (int mt = 0; mt < 2; ++mt) {
#pragma unroll
        for (int s = 0; s < 2; ++s) {
            const float* p = xbase + mt * 16 * ND + s * 32 + q * 8;
            float4 u0 = *(const float4*)(p);
            float4 u1 = *(const float4*)(p + 4);
            float xv[8] = {-u0.x, -u0.y, -u0.z, -u0.w, -u1.x, -u1.y, -u1.z, -u1.w};
            bf16x8 hh, ll;
#pragma unroll
            for (int jj = 0; jj < 8; ++jj) {
                unsigned short hb = f2bf_rne(xv[jj]);
                unsigned short lb = f2bf_rne(xv[jj] - bf2f(hb));
                hh[jj] = (short)hb;
                ll[jj] = (short)lb;
            }
            ah[mt][s] = hh;
            al[mt][s] = ll;
        }
    }

    // ---- prep unit (f, kq=xt): transpose [64 d][16 k] + split + norms.
    // bstage reused as the fp32 transpose tile (4.25 KB, pad 17 vs banks).
    {
        float* __restrict__ tl = (float*)&bstage[0][0];    // [64][17]
        const int k0 = xt * 16;
        const float* __restrict__ wf = w + (size_t)f * ND * NK;
        const int d = tid >> 2, c4 = tid & 3;
        const float4 v4 = *(const float4*)(wf + (size_t)d * NK + k0 + c4 * 4);
        tl[d * 17 + c4 * 4 + 0] = v4.x;
        tl[d * 17 + c4 * 4 + 1] = v4.y;
        tl[d * 17 + c4 * 4 + 2] = v4.z;
        tl[d * 17 + c4 * 4 + 3] = v4.w;
        __syncthreads();

        const int k = tid >> 4, p = tid & 15;   // k in [0,16), d-range p*4..+3
        float v[4];
        float s = 0.0f;
#pragma unroll
        for (int j4 = 0; j4 < 4; ++j4) {
            v[j4] = tl[(p * 4 + j4) * 17 + k];
            s = fmaf(v[j4], v[j4], s);
        }
        s += __shfl_xor(s, 1, 64);
        s += __shfl_xor(s, 2, 64);
        s += __shfl_xor(s, 4, 64);
        s += __shfl_xor(s, 8, 64);
        if (p == 0) w2h[f * NK + k0 + k] = 0.5f * s;

        const size_t rowo = ((size_t)f * NK + k0 + k) * ND + p * 4;
        unsigned short hh[4], ll[4];
#pragma unroll
        for (int j4 = 0; j4 < 4; ++j4) {
            hh[j4] = f2bf_rne(v[j4]);
            ll[j4] = f2bf_rne(v[j4] - bf2f(hh[j4]));
        }
        *(float4*)(wt + rowo)  = make_float4(v[0], v[1], v[2], v[3]);
        *(ushort4*)(wh + rowo) = make_ushort4(hh[0], hh[1], hh[2], hh[3]);
        *(ushort4*)(wl + rowo) = make_ushort4(ll[0], ll[1], ll[2], ll[3]);
    }

    // ---- f-group sync: wait for all 32 prep units of this f. Release
    // fences order the codebook stores before the signal; acquire fences
    // invalidate stale L1/L2 before the staged reads (Guideline 16).
    __threadfence();
    __syncthreads();
    if (tid == 0) {
        atomicAdd(&syncws[f], 1u);
        while (atomicAdd(&syncws[f], 0u) < 32u) {
            __builtin_amdgcn_s_sleep(2);
        }
    }
    __syncthreads();
    __threadfence();

    for (int t = tid; t < NK; t += 256) w2s[t] = w2h[f * NK + t];

    const unsigned short* __restrict__ whf = wh + (size_t)f * NK * ND;
    const unsigned short* __restrict__ wlf = wl + (size_t)f * NK * ND;

    // slim 2-channel packed top-2: k1 = min key, k2 = 2nd-min key
    float k1[8], k2[8];
#pragma unroll
    for (int ri = 0; ri < 8; ++ri) { k1[ri] = INFINITY; k2[ri] = INFINITY; }

    // ---- stage supertile st (32 cols) into bstage[pb]: 8 chunks of 1KB,
    // 2 per wave. chunk c = tl*4 + sg*2 + (lo/hi). lane-linear dest.
#define STAGE(st, pb) do {                                                  \
    _Pragma("unroll")                                                       \
    for (int rep = 0; rep < 2; ++rep) {                                     \
        const int c  = wave * 2 + rep;                                      \
        const int tl = c >> 2;                                              \
        const int sg = (c >> 1) & 1;                                        \
        const unsigned short* src = ((c & 1) ? wlf : whf) +                 \
            (size_t)((st) * 32 + tl * 16 + lc) * ND + q * 8 + sg * 32;      \
        gload_lds16(src, &bstage[pb][c * 512]);                             \
    }                                                                       \
} while (0)

    STAGE(0, 0);

    for (int st = 0; st < 16; ++st) {
        __syncthreads();                 // drains this st's loads (vmcnt)
        if (st < 15) STAGE(st + 1, (st + 1) & 1);
        const unsigned short* __restrict__ bb = &bstage[st & 1][0];

#pragma unroll
        for (int tl = 0; tl < 2; ++tl) {
            const int col = st * 32 + tl * 16 + lc;
            bf16x8 bh0 = *(const bf16x8*)(bb + (tl * 4 + 0) * 512 + lane * 8);
            bf16x8 bl0 = *(const bf16x8*)(bb + (tl * 4 + 1) * 512 + lane * 8);
            bf16x8 bh1 = *(const bf16x8*)(bb + (tl * 4 + 2) * 512 + lane * 8);
            bf16x8 bl1 = *(const bf16x8*)(bb + (tl * 4 + 3) * 512 + lane * 8);
            const float w2 = w2s[col];
#pragma unroll
            for (int mt = 0; mt < 2; ++mt) {
                f32x4 c = {w2, w2, w2, w2};
                c = __builtin_amdgcn_mfma_f32_16x16x32_bf16(ah[mt][0], bh0, c, 0, 0, 0);
                c = __builtin_amdgcn_mfma_f32_16x16x32_bf16(ah[mt][1], bh1, c, 0, 0, 0);
                c = __builtin_amdgcn_mfma_f32_16x16x32_bf16(ah[mt][0], bl0, c, 0, 0, 0);
                c = __builtin_amdgcn_mfma_f32_16x16x32_bf16(ah[mt][1], bl1, c, 0, 0, 0);
                c = __builtin_amdgcn_mfma_f32_16x16x32_bf16(al[mt][0], bh0, c, 0, 0, 0);
                c = __builtin_amdgcn_mfma_f32_16x16x32_bf16(al[mt][1], bh1, c, 0, 0, 0);
#pragma unroll
                for (int r = 0; r < 4; ++r) {
                    const int ri = mt * 4 + r;
                    // packed key: col in low 9 mantissa bits; 3 VALU/score
                    const float key = __uint_as_float(
                        (__float_as_uint(c[r]) & 0xFFFFFE00u) | (unsigned int)col);
                    k2[ri] = __builtin_amdgcn_fmed3f(key, k1[ri], k2[ri]);
                    k1[ri] = fminf(key, k1[ri]);
                }
            }
        }
    }

    // ---- merge packed top-2 across the 16 lanes holding each row ----
#pragma unroll
    for (int ri = 0; ri < 8; ++ri) {
        float a1 = k1[ri], a2 = k2[ri];
#pragma unroll
        for (int off = 1; off < 16; off <<= 1) {
            const float b1 = __shfl_xor(a1, off, 64);
            const float b2 = __shfl_xor(a2, off, 64);
            a2 = fminf(fminf(a2, b2), fmaxf(a1, b1));
            a1 = fminf(a1, b1);
        }
        k1[ri] = a1; k2[ri] = a2;
    }

    if (lc == 0) {
#pragma unroll
        for (int mt = 0; mt < 2; ++mt) {
#pragma unroll
            for (int r = 0; r < 4; ++r) {
                const int ri = mt * 4 + r;
                const int lr = wave * 32 + mt * 16 + q * 4 + r;  // block-local row
                const unsigned int u1 = __float_as_uint(k1[ri]);
                const unsigned int u2 = __float_as_uint(k2[ri]);
                lds_key[lr] = u1 & 0x1FFu;
                const float s1 = __uint_as_float(u1 & 0xFFFFFE00u);
                const float s2 = __uint_as_float(u2 & 0xFFFFFE00u);
                lds_flag[lr] = (s2 - s1 < RESCUE_TAU) ? 1 : 0;
            }
        }
    }
    __syncthreads();

    // ---- wave-local exact rescue of flagged rows ----
    {
        const int lr32 = wave * 32 + (lane & 31);
        const int fl = (lane < 32) ? lds_flag[lr32] : 0;
        unsigned long long mm = __ballot(fl != 0);
        const float* __restrict__ wtf = wt + (size_t)f * NK * ND;
        while (mm) {
            const int r = __ffsll(mm) - 1;
            mm &= mm - 1;
            const int grow = g0b + wave * 32 + r;
            const float* __restrict__ xr = x_in + (size_t)grow * ND;
            unsigned long long best = 0xFFFFFFFFFFFFFFFFULL;
#pragma unroll 1
            for (int jj = 0; jj < 8; ++jj) {
                const int col = jj * 64 + lane;
                const float* __restrict__ wr = wtf + (size_t)col * ND;
                float t = w2s[col];
#pragma unroll
                for (int d = 0; d < ND; d += 4) {
                    float4 xv = *(const float4*)(xr + d);   // broadcast
                    float4 wv = *(const float4*)(wr + d);
                    t = fmaf(-xv.x, wv.x, t);
                    t = fmaf(-xv.y, wv.y, t);
                    t = fmaf(-xv.z, wv.z, t);
                    t = fmaf(-xv.w, wv.w, t);
                }
                unsigned int u = __float_as_uint(t);
                u ^= (unsigned int)((int)u >> 31) | 0x80000000u;
                const unsigned long long key =
                    ((unsigned long long)u << 32) | (unsigned int)col;
                best = key < best ? key : best;
            }
#pragma unroll
            for (int off = 32; off > 0; off >>= 1) {
                const unsigned long long o = __shfl_xor(best, off, 64);
                best = o < best ? o : best;
            }
            if (lane == 0) lds_key[wave * 32 + r] = (unsigned int)(best & 0x1FFu);
        }
    }
    __syncthreads();

    // ---- gather + loss: 2 threads per row (32 floats each) ----
    {
        const int row_l = tid >> 1;
        const int part  = tid & 1;
        const int grow  = g0b + row_l;
        const unsigned int k = lds_key[row_l];
        const float* __restrict__ q32 = wt + ((size_t)f * NK + k) * ND + part * 32;
        const float* __restrict__ x32 = x_in + (size_t)grow * ND + part * 32;
        float* __restrict__ o32       = out + (size_t)grow * ND + part * 32;

        float lsum = 0.0f;
#pragma unroll
        for (int jj = 0; jj < 8; ++jj) {
            float4 qv = *(const float4*)(q32 + 4 * jj);
            float4 xv = *(const float4*)(x32 + 4 * jj);
            const float dx0 = qv.x - xv.x;
            const float dx1 = qv.y - xv.y;
            const float dx2 = qv.z - xv.z;
            const float dx3 = qv.w - xv.w;
            lsum = fmaf(dx0, dx0, lsum);
            lsum = fmaf(dx1, dx1, lsum);
            lsum = fmaf(dx2, dx2, lsum);
            lsum = fmaf(dx3, dx3, lsum);
            *(float4*)(o32 + 4 * jj) = qv;
        }

#pragma unroll
        for (int off = 32; off > 0; off >>= 1) {
            lsum += __shfl_down(lsum, off, 64);
        }
        if ((tid & 63) == 0) wsum[tid >> 6] = lsum;
        __syncthreads();
        if (tid == 0) {
            atomicAdd((float*)&syncws[33],
                      (wsum[0] + wsum[1] + wsum[2] + wsum[3]) * LOSS_SCALE);
            __threadfence();
            const unsigned int old = atomicAdd(&syncws[32], 1u);
            if (old == 1023u) {            // last block finalizes the scalar
                __threadfence();
                const float total = atomicAdd((float*)&syncws[33], 0.0f);
                *loss_slot = total;
            }
        }
    }
}

extern "C" void kernel_launch(void* const* d_in, const int* in_sizes, int n_in,
                              void* d_out, int out_size, void* d_ws, size_t ws_size,
                              hipStream_t stream) {
    const float* x_in = (const float*)d_in[0];  // [F, N, D] fp32
    const float* w    = (const float*)d_in[1];  // [F, D, K] fp32
    float* out        = (float*)d_out;          // [F*N*D] output then [1] loss

    // ws: [0..31] per-f sync ctrs, [32] done ctr, [33] loss accum (256B pad)
    unsigned int* syncws = (unsigned int*)d_ws;
    float* wt  = (float*)((char*)d_ws + 256);                    // 4 MB
    float* w2h = wt + (size_t)NF * NK * ND;                      // 64 KB
    unsigned short* wh = (unsigned short*)(w2h + NF * NK);       // 2 MB
    unsigned short* wl = wh + (size_t)NF * NK * ND;              // 2 MB

    float* loss_slot = out + (size_t)NF * NN * ND;

    hipMemsetAsync(d_ws, 0, 256, stream);   // capture-safe memset node

    vq_fused<<<NF * NN / 128, 256, 0, stream>>>(x_in, w, wt, wh, wl, w2h,
                                                syncws, out, loss_slot);
}

// Round 9
// 146.026 us; speedup vs baseline: 2.7192x; 2.7192x over previous
//
#include <hip/hip_runtime.h>
#include <math.h>

#define NF 32
#define NN 4096
#define ND 64
#define NK 512

// loss = q_latent + 0.25 * e_latent = 1.25 * mean((q - x)^2)
#define LOSS_SCALE (1.25f / (float)(NF * NN * ND))
// rescue margin, tested in the PACKED-KEY domain: exact-score margin
// TAU=3e-4 (3-term split-bf16 err) + 2x col-pack trunc quantum
// (|s| <= ~3 -> q <= 1.3e-4): flag if s2' - s1' < 5.5e-4. Strictly
// conservative vs the exact-gap test (ties/collisions always flagged).
// Validated in R8 run (passed, absmax 4.88e-4 unchanged).
#define RESCUE_TAU 5.5e-4f

typedef short bf16x8 __attribute__((ext_vector_type(8)));
typedef float f32x4 __attribute__((ext_vector_type(4)));

static __device__ __forceinline__ unsigned short f2bf_rne(float f) {
    unsigned int u = __float_as_uint(f);
    u += 0x7FFFu + ((u >> 16) & 1u);
    return (unsigned short)(u >> 16);
}
static __device__ __forceinline__ float bf2f(unsigned short h) {
    return __uint_as_float(((unsigned int)h) << 16);
}

// async global->LDS: 16B per lane, dest = wave-uniform base + lane*16
static __device__ __forceinline__ void gload_lds16(const void* g, void* l) {
    __builtin_amdgcn_global_load_lds(
        (const __attribute__((address_space(1))) unsigned int*)g,
        (__attribute__((address_space(3))) unsigned int*)l, 16, 0, 0);
}

// ---------------------------------------------------------------------------
// prep_w (R7, proven): LDS-transpose for coalesced w reads. Block =
// (f, 64-col k-group); phase 1 reads [64 d][64 k] tile with full-64B
// coalesced loads into LDS; phase 2 reads transposed, computes bf16 hi/lo
// split + 0.5||w||^2, writes wt/wh/wl coalesced. Zeroes loss slot. 256 blks.
// (R8 lesson: do NOT fuse this into argmin — device-scope fences/spin sync
// cost 5x the dispatch they save on CDNA4's non-coherent L2s.)
// ---------------------------------------------------------------------------
__global__ __launch_bounds__(256)
void vq_prep_w(const float* __restrict__ w, float* __restrict__ wt,
               unsigned short* __restrict__ wh, unsigned short* __restrict__ wl,
               float* __restrict__ w2h, float* __restrict__ loss_slot) {
    __shared__ float lds[64 * 65];        // +1 pad: transposed reads conflict-free
    const int t  = threadIdx.x;
    const int f  = blockIdx.x >> 3;
    const int k0 = (blockIdx.x & 7) * 64;
    const float* __restrict__ wf = w + (size_t)f * ND * NK;

    if (blockIdx.x == 0 && t == 0) *loss_slot = 0.0f;

    {   // phase 1: d = t>>2 (16 rows/wave), 4 float4 per thread
        const int d = t >> 2, qq = t & 3;
#pragma unroll
        for (int i = 0; i < 4; ++i) {
            const int c4 = qq + i * 4;    // float4 index within the 64-col row
            const float4 v = *(const float4*)(wf + (size_t)d * NK + k0 + c4 * 4);
            lds[d * 65 + c4 * 4 + 0] = v.x;
            lds[d * 65 + c4 * 4 + 1] = v.y;
            lds[d * 65 + c4 * 4 + 2] = v.z;
            lds[d * 65 + c4 * 4 + 3] = v.w;
        }
    }
    __syncthreads();

    // phase 2: thread owns (k = t>>2, d-range p*16..p*16+15)
    const int k = t >> 2, p = t & 3;
    float v[16];
    float s = 0.0f;
#pragma unroll
    for (int j = 0; j < 16; ++j) {
        v[j] = lds[(p * 16 + j) * 65 + k];
        s = fmaf(v[j], v[j], s);
    }
    s += __shfl_xor(s, 1, 64);            // 4 threads share one k
    s += __shfl_xor(s, 2, 64);
    if (p == 0) w2h[f * NK + k0 + k] = 0.5f * s;

    const size_t rowo = ((size_t)f * NK + k0 + k) * ND + p * 16;
    unsigned short hh[16], ll[16];
#pragma unroll
    for (int j = 0; j < 16; ++j) {
        hh[j] = f2bf_rne(v[j]);
        ll[j] = f2bf_rne(v[j] - bf2f(hh[j]));
    }
#pragma unroll
    for (int i = 0; i < 4; ++i) {
        *(float4*)(wt + rowo + i * 4) =
            make_float4(v[i*4+0], v[i*4+1], v[i*4+2], v[i*4+3]);
        *(ushort4*)(wh + rowo + i * 4) =
            make_ushort4(hh[i*4+0], hh[i*4+1], hh[i*4+2], hh[i*4+3]);
        *(ushort4*)(wl + rowo + i * 4) =
            make_ushort4(ll[i*4+0], ll[i*4+1], ll[i*4+2], ll[i*4+3]);
    }
}

// ---------------------------------------------------------------------------
// argmin FUSED v9 = R7 (148us total, best known) + two local changes:
//  1) 64-COL SUPERTILES: 8 barrier intervals instead of 16. Per-interval
//     compute doubles to ~550-600 cyc >= L2/LLC load latency, so the
//     double-buffer slack (one interval) finally covers the prefetch; the
//     16x-exposed per-barrier latency gap was the main-loop's dominant
//     stall (R4: more vmcnt slack at same interval length = null; R5
//     ablation: no single component dominates -> the interval structure
//     itself is the cost). LDS 2x16KB dbuf -> 34.7 KB, still 4 blocks/CU.
//  2) SLIM 2-channel packed top-2 (validated R8): pack+med3+min =
//     3 VALU/score vs 4, -8 VGPRs; rescue flag from masked-key gap with
//     RESCUE_TAU (conservative).
// Phases after the loop unchanged from R7: merge -> in-LDS keys/flags ->
// wave-local exact rescue -> gather + loss partial -> atomicAdd.
// ---------------------------------------------------------------------------
__global__ __launch_bounds__(256, 4)
void vq_argmin(const float* __restrict__ x_in,
               const unsigned short* __restrict__ wh,
               const unsigned short* __restrict__ wl,
               const float* __restrict__ wt,
               const float* __restrict__ w2h,
               float* __restrict__ out,
               float* __restrict__ loss_slot) {
    const int b    = blockIdx.x;          // [0, 1024)
    const int j    = b >> 3;              // [0, 128)
    const int f    = (b & 7) * 4 + (j & 3);
    const int xt   = j >> 2;              // [0, 32)
    const int tid  = threadIdx.x;
    const int wave = tid >> 6;
    const int lane = tid & 63;
    const int lc   = lane & 15;
    const int q    = lane >> 4;
    const int n0   = xt * 128 + wave * 32;   // wave's private 32 rows
    const int g0b  = f * NN + xt * 128;      // block's global row base

    __shared__ float w2s[NK];                                 // 2 KB
    __shared__ __align__(16) unsigned short bstage[2][8192];  // 2 x 16 KB
    __shared__ unsigned int lds_key[128];                     // 512 B
    __shared__ unsigned char lds_flag[128];                   // 128 B
    __shared__ float wsum[4];

    for (int t = tid; t < NK; t += 256) w2s[t] = w2h[f * NK + t];

    // ---- A-frags: 32 rows' (-x), split to bf16 hi/lo in-register.
    bf16x8 ah[2][2], al[2][2];
    const float* __restrict__ xbase = x_in + ((size_t)f * NN + n0 + lc) * ND;
#pragma unroll
    for (int mt = 0; mt < 2; ++mt) {
#pragma unroll
        for (int s = 0; s < 2; ++s) {
            const float* p = xbase + mt * 16 * ND + s * 32 + q * 8;
            float4 u0 = *(const float4*)(p);
            float4 u1 = *(const float4*)(p + 4);
            float xv[8] = {-u0.x, -u0.y, -u0.z, -u0.w, -u1.x, -u1.y, -u1.z, -u1.w};
            bf16x8 hh, ll;
#pragma unroll
            for (int jj = 0; jj < 8; ++jj) {
                unsigned short hb = f2bf_rne(xv[jj]);
                unsigned short lb = f2bf_rne(xv[jj] - bf2f(hb));
                hh[jj] = (short)hb;
                ll[jj] = (short)lb;
            }
            ah[mt][s] = hh;
            al[mt][s] = ll;
        }
    }

    const unsigned short* __restrict__ whf = wh + (size_t)f * NK * ND;
    const unsigned short* __restrict__ wlf = wl + (size_t)f * NK * ND;

    // slim 2-channel packed top-2: k1 = min key, k2 = 2nd-min key
    float k1[8], k2[8];
#pragma unroll
    for (int ri = 0; ri < 8; ++ri) { k1[ri] = INFINITY; k2[ri] = INFINITY; }

    // ---- stage 64-col supertile st into bstage[pb]: 16 chunks of 1KB,
    // 4 per wave. chunk c: tl = c>>2 (16-col tile), sg = (c>>1)&1 (d-half),
    // c&1 = lo/hi. lane-linear dest (global_load_lds requirement).
#define STAGE(st, pb) do {                                                  \
    _Pragma("unroll")                                                       \
    for (int rep = 0; rep < 4; ++rep) {                                     \
        const int c  = wave * 4 + rep;                                      \
        const int tl = c >> 2;                                              \
        const int sg = (c >> 1) & 1;                                        \
        const unsigned short* src = ((c & 1) ? wlf : whf) +                 \
            (size_t)((st) * 64 + tl * 16 + lc) * ND + q * 8 + sg * 32;      \
        gload_lds16(src, &bstage[pb][c * 512]);                             \
    }                                                                       \
} while (0)

    STAGE(0, 0);

    for (int st = 0; st < 8; ++st) {
        __syncthreads();                 // drains this st's loads (vmcnt)
        if (st < 7) STAGE(st + 1, (st + 1) & 1);
        const unsigned short* __restrict__ bb = &bstage[st & 1][0];

#pragma unroll
        for (int tl = 0; tl < 4; ++tl) {
            const int col = st * 64 + tl * 16 + lc;
            bf16x8 bh0 = *(const bf16x8*)(bb + (tl * 4 + 0) * 512 + lane * 8);
            bf16x8 bl0 = *(const bf16x8*)(bb + (tl * 4 + 1) * 512 + lane * 8);
            bf16x8 bh1 = *(const bf16x8*)(bb + (tl * 4 + 2) * 512 + lane * 8);
            bf16x8 bl1 = *(const bf16x8*)(bb + (tl * 4 + 3) * 512 + lane * 8);
            const float w2 = w2s[col];
#pragma unroll
            for (int mt = 0; mt < 2; ++mt) {
                f32x4 c = {w2, w2, w2, w2};
                c = __builtin_amdgcn_mfma_f32_16x16x32_bf16(ah[mt][0], bh0, c, 0, 0, 0);
                c = __builtin_amdgcn_mfma_f32_16x16x32_bf16(ah[mt][1], bh1, c, 0, 0, 0);
                c = __builtin_amdgcn_mfma_f32_16x16x32_bf16(ah[mt][0], bl0, c, 0, 0, 0);
                c = __builtin_amdgcn_mfma_f32_16x16x32_bf16(ah[mt][1], bl1, c, 0, 0, 0);
                c = __builtin_amdgcn_mfma_f32_16x16x32_bf16(al[mt][0], bh0, c, 0, 0, 0);
                c = __builtin_amdgcn_mfma_f32_16x16x32_bf16(al[mt][1], bh1, c, 0, 0, 0);
#pragma unroll
                for (int r = 0; r < 4; ++r) {
                    const int ri = mt * 4 + r;
                    // packed key: col in low 9 mantissa bits; 3 VALU/score
                    const float key = __uint_as_float(
                        (__float_as_uint(c[r]) & 0xFFFFFE00u) | (unsigned int)col);
                    k2[ri] = __builtin_amdgcn_fmed3f(key, k1[ri], k2[ri]);
                    k1[ri] = fminf(key, k1[ri]);
                }
            }
        }
    }

    // ---- merge packed top-2 across the 16 lanes holding each row ----
#pragma unroll
    for (int ri = 0; ri < 8; ++ri) {
        float a1 = k1[ri], a2 = k2[ri];
#pragma unroll
        for (int off = 1; off < 16; off <<= 1) {
            const float b1 = __shfl_xor(a1, off, 64);
            const float b2 = __shfl_xor(a2, off, 64);
            a2 = fminf(fminf(a2, b2), fmaxf(a1, b1));
            a1 = fminf(a1, b1);
        }
        k1[ri] = a1; k2[ri] = a2;
    }

    if (lc == 0) {
#pragma unroll
        for (int mt = 0; mt < 2; ++mt) {
#pragma unroll
            for (int r = 0; r < 4; ++r) {
                const int ri = mt * 4 + r;
                const int lr = wave * 32 + mt * 16 + q * 4 + r;  // block-local row
                const unsigned int u1 = __float_as_uint(k1[ri]);
                const unsigned int u2 = __float_as_uint(k2[ri]);
                lds_key[lr] = u1 & 0x1FFu;
                const float s1 = __uint_as_float(u1 & 0xFFFFFE00u);
                const float s2 = __uint_as_float(u2 & 0xFFFFFE00u);
                lds_flag[lr] = (s2 - s1 < RESCUE_TAU) ? 1 : 0;
            }
        }
    }
    __syncthreads();

    // ---- wave-local exact rescue of flagged rows ----
    {
        const int lr32 = wave * 32 + (lane & 31);
        const int fl = (lane < 32) ? lds_flag[lr32] : 0;
        unsigned long long mm = __ballot(fl != 0);
        const float* __restrict__ wtf = wt + (size_t)f * NK * ND;
        while (mm) {
            const int r = __ffsll(mm) - 1;
            mm &= mm - 1;
            const int grow = g0b + wave * 32 + r;
            const float* __restrict__ xr = x_in + (size_t)grow * ND;
            unsigned long long best = 0xFFFFFFFFFFFFFFFFULL;
#pragma unroll 1
            for (int jj = 0; jj < 8; ++jj) {
                const int col = jj * 64 + lane;
                const float* __restrict__ wr = wtf + (size_t)col * ND;
                float t = w2s[col];
#pragma unroll
                for (int d = 0; d < ND; d += 4) {
                    float4 xv = *(const float4*)(xr + d);   // broadcast
                    float4 wv = *(const float4*)(wr + d);
                    t = fmaf(-xv.x, wv.x, t);
                    t = fmaf(-xv.y, wv.y, t);
                    t = fmaf(-xv.z, wv.z, t);
                    t = fmaf(-xv.w, wv.w, t);
                }
                unsigned int u = __float_as_uint(t);
                u ^= (unsigned int)((int)u >> 31) | 0x80000000u;
                const unsigned long long key =
                    ((unsigned long long)u << 32) | (unsigned int)col;
                best = key < best ? key : best;
            }
#pragma unroll
            for (int off = 32; off > 0; off >>= 1) {
                const unsigned long long o = __shfl_xor(best, off, 64);
                best = o < best ? o : best;
            }
            if (lane == 0) lds_key[wave * 32 + r] = (unsigned int)(best & 0x1FFu);
        }
    }
    __syncthreads();

    // ---- gather + loss: 2 threads per row (32 floats each) ----
    {
        const int row_l = tid >> 1;
        const int part  = tid & 1;
        const int grow  = g0b + row_l;
        const unsigned int k = lds_key[row_l];
        const float* __restrict__ q32 = wt + ((size_t)f * NK + k) * ND + part * 32;
        const float* __restrict__ x32 = x_in + (size_t)grow * ND + part * 32;
        float* __restrict__ o32       = out + (size_t)grow * ND + part * 32;

        float lsum = 0.0f;
#pragma unroll
        for (int jj = 0; jj < 8; ++jj) {
            float4 qv = *(const float4*)(q32 + 4 * jj);
            float4 xv = *(const float4*)(x32 + 4 * jj);
            const float dx0 = qv.x - xv.x;
            const float dx1 = qv.y - xv.y;
            const float dx2 = qv.z - xv.z;
            const float dx3 = qv.w - xv.w;
            lsum = fmaf(dx0, dx0, lsum);
            lsum = fmaf(dx1, dx1, lsum);
            lsum = fmaf(dx2, dx2, lsum);
            lsum = fmaf(dx3, dx3, lsum);
            *(float4*)(o32 + 4 * jj) = qv;
        }

#pragma unroll
        for (int off = 32; off > 0; off >>= 1) {
            lsum += __shfl_down(lsum, off, 64);
        }
        if ((tid & 63) == 0) wsum[tid >> 6] = lsum;
        __syncthreads();
        if (tid == 0) {
            atomicAdd(loss_slot,
                      (wsum[0] + wsum[1] + wsum[2] + wsum[3]) * LOSS_SCALE);
        }
    }
}

extern "C" void kernel_launch(void* const* d_in, const int* in_sizes, int n_in,
                              void* d_out, int out_size, void* d_ws, size_t ws_size,
                              hipStream_t stream) {
    const float* x_in = (const float*)d_in[0];  // [F, N, D] fp32
    const float* w    = (const float*)d_in[1];  // [F, D, K] fp32
    float* out        = (float*)d_out;          // [F*N*D] output then [1] loss

    float* wt  = (float*)d_ws;                                   // 4 MB
    float* w2h = wt + (size_t)NF * NK * ND;                      // 64 KB
    unsigned short* wh = (unsigned short*)(w2h + NF * NK);       // 2 MB
    unsigned short* wl = wh + (size_t)NF * NK * ND;              // 2 MB

    float* loss_slot = out + (size_t)NF * NN * ND;

    vq_prep_w<<<NF * 8, 256, 0, stream>>>(w, wt, wh, wl, w2h, loss_slot);

    vq_argmin<<<NF * NN / 128, 256, 0, stream>>>(x_in, wh, wl, wt, w2h,
                                                 out, loss_slot);
}